// Round 6
// baseline (25.957 us; speedup 1.0000x reference)
//
#include <hip/hip_runtime.h>

// MedianPool2d 3x3 stride-1 reflect-pad on (16,3,512,512) fp32.
// R6 = R5 with the nontemporal-store compile fix (clang ext_vector_type
// instead of HIP_vector_type for the builtin).
//  - R3 wave-per-row structure (no XCD swizzle: measured regression).
//  - RPT 8: 10 rows loaded / 8 stored (1.25 load-rows per output row).
//  - nontemporal output stores: output never re-read; keep the 50 MB
//    write stream from evicting the L3-resident input between replays.

static constexpr int H = 512;
static constexpr int W = 512;
static constexpr int RPT = 8;          // output rows per wave

typedef float floatx4 __attribute__((ext_vector_type(4)));

__device__ __forceinline__ float min3f(float a, float b, float c) {
    return fminf(fminf(a, b), c);            // v_min3_f32
}
__device__ __forceinline__ float max3f(float a, float b, float c) {
    return fmaxf(fmaxf(a, b), c);            // v_max3_f32
}
__device__ __forceinline__ float med3f(float a, float b, float c) {
    return __builtin_amdgcn_fmed3f(a, b, c); // v_med3_f32 (NaN-free inputs)
}

__global__ void __launch_bounds__(256)
median3x3_kernel(const float* __restrict__ x, float* __restrict__ out) {
    int wave  = (blockIdx.x * blockDim.x + threadIdx.x) >> 6;
    int lane  = threadIdx.x & 63;
    int rblk  = wave & (H / RPT - 1);      // 0..63
    int plane = wave >> 6;                 // 48 planes

    int r0 = rblk * RPT;
    const float* base  = x   + (size_t)plane * H * W;
    float*       obase = out + (size_t)plane * H * W;
    int c0 = lane * 8;

    float va[3][10];                       // rolling 3-row buffer, 10 cols w/ halo

#pragma unroll
    for (int j = 0; j < RPT + 2; ++j) {
        int rr = r0 - 1 + j;
        rr = (rr < 0) ? 1 : ((rr >= H) ? (2 * H - 2 - rr) : rr);  // reflect pad=1
        const float* p = base + (size_t)rr * W + c0;
        float4 a = *reinterpret_cast<const float4*>(p);
        float4 b = *reinterpret_cast<const float4*>(p + 4);

        // halo across lanes: left = lane-1's col 8i-1 (=its b.w),
        //                    right = lane+1's col 8i+8 (=its a.x)
        float lft = __shfl_up(b.w, 1);
        float rgt = __shfl_down(a.x, 1);
        if (lane == 0)  lft = a.y;         // reflect col -1 -> col 1
        if (lane == 63) rgt = b.z;         // reflect col 512 -> col 510

        float* row = va[j % 3];
        row[0] = lft;
        row[1] = a.x; row[2] = a.y; row[3] = a.z; row[4] = a.w;
        row[5] = b.x; row[6] = b.y; row[7] = b.z; row[8] = b.w;
        row[9] = rgt;

        if (j >= 2) {
            const float* t0 = va[(j - 2) % 3];
            const float* t1 = va[(j - 1) % 3];
            const float* t2 = va[j % 3];
            float cmin[10], cmed[10], cmax[10];
#pragma unroll
            for (int c = 0; c < 10; ++c) {
                float u = t0[c], v = t1[c], w = t2[c];
                cmin[c] = min3f(u, v, w);
                cmed[c] = med3f(u, v, w);
                cmax[c] = max3f(u, v, w);
            }
            float res[8];
#pragma unroll
            for (int k = 0; k < 8; ++k) {
                res[k] = med3f(max3f(cmin[k], cmin[k + 1], cmin[k + 2]),
                               med3f(cmed[k], cmed[k + 1], cmed[k + 2]),
                               min3f(cmax[k], cmax[k + 1], cmax[k + 2]));
            }
            float* op = obase + (size_t)(r0 + j - 2) * W + c0;
            floatx4 lo = { res[0], res[1], res[2], res[3] };
            floatx4 hi = { res[4], res[5], res[6], res[7] };
            __builtin_nontemporal_store(lo, reinterpret_cast<floatx4*>(op));
            __builtin_nontemporal_store(hi, reinterpret_cast<floatx4*>(op + 4));
        }
    }
}

extern "C" void kernel_launch(void* const* d_in, const int* in_sizes, int n_in,
                              void* d_out, int out_size, void* d_ws, size_t ws_size,
                              hipStream_t stream) {
    const float* x = (const float*)d_in[0];
    float* out = (float*)d_out;
    int total_waves = out_size / (RPT * W);        // 3072
    int threads = 256;
    int blocks = total_waves * 64 / threads;       // 768
    median3x3_kernel<<<blocks, threads, 0, stream>>>(x, out);
}

// Round 7
// 23.672 us; speedup vs baseline: 1.0965x; 1.0965x over previous
//
#include <hip/hip_runtime.h>

// MedianPool2d 3x3 stride-1 reflect-pad on (16,3,512,512) fp32.
// R7 = R3 (best measured: 23.4us) + __launch_bounds__(256, 6).
// Model: harness fills 268MB between replays -> L3 fully evicted -> every
// replay reads input from HBM. Floor ~16-17us @6.29TB/s for 100.6MB.
// R3's gap is latency hiding: est. ~100-128 VGPR -> only 4-5 waves/SIMD
// resident. Forcing VGPR<=85 makes all 6 launched waves/SIMD resident.
//  - RPT=4, wave-per-row, shuffle halo, plain float4 stores (nt regressed),
//    no XCD swizzle (regressed).

static constexpr int H = 512;
static constexpr int W = 512;
static constexpr int RPT = 4;          // output rows per wave

__device__ __forceinline__ float min3f(float a, float b, float c) {
    return fminf(fminf(a, b), c);            // v_min3_f32
}
__device__ __forceinline__ float max3f(float a, float b, float c) {
    return fmaxf(fmaxf(a, b), c);            // v_max3_f32
}
__device__ __forceinline__ float med3f(float a, float b, float c) {
    return __builtin_amdgcn_fmed3f(a, b, c); // v_med3_f32 (NaN-free inputs)
}

__global__ void __launch_bounds__(256, 6)
median3x3_kernel(const float* __restrict__ x, float* __restrict__ out) {
    int wave  = (blockIdx.x * blockDim.x + threadIdx.x) >> 6;
    int lane  = threadIdx.x & 63;
    int rblk  = wave & (H / RPT - 1);      // 0..127
    int plane = wave >> 7;                 // 48 planes

    int r0 = rblk * RPT;
    const float* base  = x   + (size_t)plane * H * W;
    float*       obase = out + (size_t)plane * H * W;
    int c0 = lane * 8;

    float va[3][10];                       // rolling 3-row buffer, 10 cols w/ halo

#pragma unroll
    for (int j = 0; j < RPT + 2; ++j) {
        int rr = r0 - 1 + j;
        rr = (rr < 0) ? 1 : ((rr >= H) ? (2 * H - 2 - rr) : rr);  // reflect pad=1
        const float* p = base + (size_t)rr * W + c0;
        float4 a = *reinterpret_cast<const float4*>(p);
        float4 b = *reinterpret_cast<const float4*>(p + 4);

        // halo across lanes: left = lane-1's col 8i-1 (=its b.w),
        //                    right = lane+1's col 8i+8 (=its a.x)
        float lft = __shfl_up(b.w, 1);
        float rgt = __shfl_down(a.x, 1);
        if (lane == 0)  lft = a.y;         // reflect col -1 -> col 1
        if (lane == 63) rgt = b.z;         // reflect col 512 -> col 510

        float* row = va[j % 3];
        row[0] = lft;
        row[1] = a.x; row[2] = a.y; row[3] = a.z; row[4] = a.w;
        row[5] = b.x; row[6] = b.y; row[7] = b.z; row[8] = b.w;
        row[9] = rgt;

        if (j >= 2) {
            const float* t0 = va[(j - 2) % 3];
            const float* t1 = va[(j - 1) % 3];
            const float* t2 = va[j % 3];
            float cmin[10], cmed[10], cmax[10];
#pragma unroll
            for (int c = 0; c < 10; ++c) {
                float u = t0[c], v = t1[c], w = t2[c];
                cmin[c] = min3f(u, v, w);
                cmed[c] = med3f(u, v, w);
                cmax[c] = max3f(u, v, w);
            }
            float res[8];
#pragma unroll
            for (int k = 0; k < 8; ++k) {
                res[k] = med3f(max3f(cmin[k], cmin[k + 1], cmin[k + 2]),
                               med3f(cmed[k], cmed[k + 1], cmed[k + 2]),
                               min3f(cmax[k], cmax[k + 1], cmax[k + 2]));
            }
            float* op = obase + (size_t)(r0 + j - 2) * W + c0;
            *reinterpret_cast<float4*>(op)     = make_float4(res[0], res[1], res[2], res[3]);
            *reinterpret_cast<float4*>(op + 4) = make_float4(res[4], res[5], res[6], res[7]);
        }
    }
}

extern "C" void kernel_launch(void* const* d_in, const int* in_sizes, int n_in,
                              void* d_out, int out_size, void* d_ws, size_t ws_size,
                              hipStream_t stream) {
    const float* x = (const float*)d_in[0];
    float* out = (float*)d_out;
    int total_waves = out_size / (RPT * W);        // 6144
    int threads = 256;
    int blocks = total_waves * 64 / threads;       // 1536
    median3x3_kernel<<<blocks, threads, 0, stream>>>(x, out);
}